// Round 5
// baseline (369.511 us; speedup 1.0000x reference)
//
#include <hip/hip_runtime.h>
#include <hip/hip_bf16.h>

#define NN 50000
#define NE 800000
#define H  64
#define AD 9

typedef __attribute__((ext_vector_type(8)))  short short8;
typedef __attribute__((ext_vector_type(16))) float f32x16;
typedef unsigned int uint;
typedef unsigned short ushort;

union U8 { short8 v; uint u[4]; ushort s[8]; };

__device__ __forceinline__ f32x16 MFMA(short8 a, short8 b, f32x16 c) {
    return __builtin_amdgcn_mfma_f32_32x32x16_bf16(a, b, c, 0, 0, 0);
}

__device__ __forceinline__ ushort f2bf(float v) {
    __hip_bfloat16 b = __float2bfloat16(v);
    return *(ushort*)&b;
}
__device__ __forceinline__ uint pkbf(float a, float b) {
    uint r;
    asm volatile("v_cvt_pk_bf16_f32 %0, %1, %2" : "=v"(r) : "v"(a), "v"(b));
    return r;
}
__device__ __forceinline__ float bflo(uint u) { return __uint_as_float(u << 16); }
__device__ __forceinline__ float bfhi(uint u) { return __uint_as_float(u & 0xffff0000u); }

__device__ __forceinline__ float swish_fast(float v) {
    return v * __builtin_amdgcn_rcpf(1.f + __expf(-v));
}

// {a,b} -> a' = {a.lo_lanes, b.lo_lanes}, b' = {a.hi_lanes, b.hi_lanes}
__device__ __forceinline__ void xhalf(uint& a, uint& b) {
    asm("v_permlane32_swap_b32 %0, %1" : "+v"(a), "+v"(b));
}

// pack 16 accum values (one 32-row C-half) into 2 bf16 frags (k=row order)
__device__ __forceinline__ void pack16(const float* y, short8* out) {
    #pragma unroll
    for (int g = 0; g < 2; ++g) {
        uint c0 = pkbf(y[g*8+0], y[g*8+1]);
        uint c1 = pkbf(y[g*8+2], y[g*8+3]);
        uint c2 = pkbf(y[g*8+4], y[g*8+5]);
        uint c3 = pkbf(y[g*8+6], y[g*8+7]);
        xhalf(c0, c2);
        xhalf(c1, c3);
        U8 q; q.u[0] = c0; q.u[1] = c1; q.u[2] = c2; q.u[3] = c3;
        out[g] = q.v;
    }
}

// ---------------- prep: x -> bf16 AND weights -> transposed/padded bf16 ----------------
__global__ void prep_all(const float* __restrict__ x, ushort* __restrict__ xb,
                         const float* __restrict__ Wm1, const float* __restrict__ Vm1,
                         const float* __restrict__ Wm2, const float* __restrict__ Vm2,
                         const float* __restrict__ Wu1, const float* __restrict__ Vu1,
                         const float* __restrict__ Wu2, const float* __restrict__ Vu2,
                         ushort* __restrict__ wbE, ushort* __restrict__ wbN) {
    const int b = blockIdx.x;
    if (b < 1563) {
        int t = b * 256 + threadIdx.x;
        if (t >= NN * H / 8) return;
        const float* p = x + (size_t)t * 8;
        U8 o;
        #pragma unroll
        for (int j = 0; j < 8; ++j) o.s[j] = f2bf(p[j]);
        *(short8*)(xb + (size_t)t * 8) = o.v;
        return;
    }
    int t = (b - 1563) * 256 + threadIdx.x;
    float v = 0.f;
    if (t < 2 * 17408) {
        int l = t / 17408, o = t % 17408;
        if (o < 10752)      { int h = o / 168, k = o % 168;            if (k < 129) v = Wm1[l*8256 + k*64 + h]; }
        else if (o < 15360) { int o2 = o-10752; int h = o2/72, k = o2%72; if (k < 64)  v = Wm2[l*4096 + k*64 + h]; }
        else if (o < 16384) { int o2 = o-15360; int h = o2/16, a = o2%16; if (a < 9)   v = Vm1[l*576 + a*64 + h]; }
        else                { int o2 = o-16384; int h = o2/16, a = o2%16; if (a < 9)   v = Vm2[l*576 + a*64 + h]; }
        wbE[t] = f2bf(v);
    } else if (t < 2 * 17408 + 2 * 15360) {
        int u = t - 2 * 17408;
        int l = u / 15360, o = u % 15360;
        if (o < 8704)       { int h = o / 136, k = o % 136;            if (k < 128) v = Wu1[l*8192 + k*64 + h]; }
        else if (o < 13312) { int o2 = o-8704;  int h = o2/72, k = o2%72; if (k < 64)  v = Wu2[l*4096 + k*64 + h]; }
        else if (o < 14336) { int o2 = o-13312; int h = o2/16, a = o2%16; if (a < 9)   v = Vu1[l*576 + a*64 + h]; }
        else                { int o2 = o-14336; int h = o2/16, a = o2%16; if (a < 9)   v = Vu2[l*576 + a*64 + h]; }
        wbN[u] = f2bf(v);
    }
}

// ---------------- CSR build ----------------
__global__ void hist_k(const int* __restrict__ ei, int* __restrict__ cnt) {
    int t = blockIdx.x * 256 + threadIdx.x;
    if (t < NE) atomicAdd(&cnt[ei[NE + t]], 1);
}

__global__ void scan1_k(const int* __restrict__ cnt, int* __restrict__ partial,
                        int* __restrict__ btot) {
    __shared__ int sh[256];
    const int b = blockIdx.x, tid = threadIdx.x, i = b * 256 + tid;
    int c = cnt[i];
    sh[tid] = c; __syncthreads();
    int run = c;
    for (int off = 1; off < 256; off <<= 1) {
        int t = (tid >= off) ? sh[tid - off] : 0;
        __syncthreads();
        run += t; sh[tid] = run; __syncthreads();
    }
    partial[i] = run - c;
    if (tid == 255) btot[b] = run;
}

__global__ void scan2_k(const int* __restrict__ btot, int* __restrict__ boff) {
    __shared__ int sh[256];
    const int tid = threadIdx.x;
    int c = (tid < 200) ? btot[tid] : 0;
    sh[tid] = c; __syncthreads();
    int run = c;
    for (int off = 1; off < 256; off <<= 1) {
        int t = (tid >= off) ? sh[tid - off] : 0;
        __syncthreads();
        run += t; sh[tid] = run; __syncthreads();
    }
    boff[tid] = run - c;
}

__global__ void scan3_k(const int* __restrict__ partial, const int* __restrict__ boff,
                        int* __restrict__ cursor) {
    int b = blockIdx.x, i = b * 256 + threadIdx.x;
    if (i < NN) cursor[i] = partial[i] + boff[b];
}

__global__ void fill_k(const int* __restrict__ ei, const float* __restrict__ edge_attr,
                       const float* __restrict__ amf, int* __restrict__ cursor,
                       ushort2* __restrict__ nbrS, uint4* __restrict__ eaLo,
                       uint* __restrict__ eaHi) {
    int e = blockIdx.x * 256 + threadIdx.x;
    if (e >= NE) return;
    const int dst = ei[NE + e], src = ei[e];
    const int pos = atomicAdd(&cursor[dst], 1);
    ushort2 nd; nd.x = (ushort)src; nd.y = (ushort)dst;
    nbrS[pos] = nd;
    float ea[AD];
    #pragma unroll
    for (int a = 0; a < AD; ++a) ea[a] = edge_attr[(size_t)e * AD + a];
    uint4 lo;
    lo.x = pkbf(ea[0], ea[1]); lo.y = pkbf(ea[2], ea[3]);
    lo.z = pkbf(ea[4], ea[5]); lo.w = pkbf(ea[6], ea[7]);
    eaLo[pos] = lo;
    eaHi[pos] = pkbf(ea[8], amf[e]);   // lo16 = ea[8], hi16 = amf
}

// ---------------- edge message compute (GEMM2 flipped: C2[e][h]) ----------------
struct YPair { f32x16 a, b; };

__device__ __forceinline__ YPair msg_compute(
    const short8 bx[8], uint4 elo, uint ehi,
    const ushort* __restrict__ W1T,
    const short8 aW2[4][2], const short8 aV1[2], const short8 aV2[2],
    const float* __restrict__ b1, float bias2_0, float bias2_1,
    int l31, int hi) {
    U8 bea;
    bea.u[0] = hi ? (ehi & 0xffffu) : elo.x;
    bea.u[1] = hi ? 0u : elo.y;
    bea.u[2] = hi ? 0u : elo.z;
    bea.u[3] = hi ? 0u : elo.w;

    // gate1 (old orientation C[h][e])
    f32x16 gA0 = {}, gA1 = {};
    gA0 = MFMA(aV1[0], bea.v, gA0);
    gA1 = MFMA(aV1[1], bea.v, gA1);

    // GEMM1: m1T[h][e] = sum_k W1[k][h] * [x_i | x_j | amf][e][k]
    f32x16 mA0 = {}, mA1 = {};
    #pragma unroll
    for (int s = 0; s < 8; ++s) {
        short8 a0 = *(const short8*)(W1T + l31 * 168 + s * 16 + hi * 8);
        short8 a1 = *(const short8*)(W1T + (l31 + 32) * 168 + s * 16 + hi * 8);
        mA0 = MFMA(a0, bx[s], mA0);
        mA1 = MFMA(a1, bx[s], mA1);
    }
    {
        U8 ba;
        ba.u[0] = hi ? 0u : (ehi >> 16);
        ba.u[1] = 0; ba.u[2] = 0; ba.u[3] = 0;
        short8 a0 = *(const short8*)(W1T + l31 * 168 + 128 + hi * 8);
        short8 a1 = *(const short8*)(W1T + (l31 + 32) * 168 + 128 + hi * 8);
        mA0 = MFMA(a0, ba.v, mA0);
        mA1 = MFMA(a1, ba.v, mA1);
    }

    // swish(m1*gate1 + b1) -> frags (k=h_in, index=e) usable as GEMM2 A-operand
    short8 bm[4];
    #pragma unroll
    for (int m = 0; m < 2; ++m) {
        const f32x16 mc = m ? mA1 : mA0;
        const f32x16 gc = m ? gA1 : gA0;
        float y[16];
        #pragma unroll
        for (int r = 0; r < 16; ++r) {
            int h0 = (r & 3) + 8 * (r >> 2) + 32 * m;
            float bb = hi ? b1[h0 + 4] : b1[h0];
            y[r] = swish_fast(fmaf(mc[r], gc[r], bb));
        }
        pack16(y, &bm[2 * m]);
    }

    // flipped gate2 + GEMM2: C[m=e][n=h_out]
    f32x16 g2a = {}, g2b = {};
    g2a = MFMA(bea.v, aV2[0], g2a);
    g2b = MFMA(bea.v, aV2[1], g2b);
    f32x16 p0 = {}, p1 = {};
    #pragma unroll
    for (int s = 0; s < 4; ++s) {
        p0 = MFMA(bm[s], aW2[s][0], p0);
        p1 = MFMA(bm[s], aW2[s][1], p1);
    }

    YPair out;
    #pragma unroll
    for (int r = 0; r < 16; ++r) {
        out.a[r] = swish_fast(fmaf(p0[r], g2a[r], bias2_0));
        out.b[r] = swish_fast(fmaf(p1[r], g2b[r], bias2_1));
    }
    return out;
}

__device__ __forceinline__ void gather_x(short8 bx[8], const ushort* __restrict__ xbf,
                                         int dst, int src, int hi) {
    const ushort* xd = xbf + (size_t)dst * H;
    const ushort* xs = xbf + (size_t)src * H;
    #pragma unroll
    for (int s = 0; s < 8; ++s)
        bx[s] = *(const short8*)((s < 4 ? xd : xs) + (s & 3) * 16 + hi * 8);
}

// in-register segmented reduce over 32 dst-sorted edges (C rows), coalesced atomics
__device__ __forceinline__ void reduce_write(const YPair& y, int dst,
                                             float* __restrict__ agg,
                                             int lane, int l31, int hi) {
    int dp = __shfl_up(dst, 1);
    bool nb = (l31 != 0) && (dst != dp);
    uint mm = (uint)__ballot(nb);   // low 32 bits; halves mirror
    int lo = 0;
    while (lo < 32) {
        int nx = mm ? (int)__builtin_ctz(mm) : 32;
        mm &= mm - 1;
        float s0 = 0.f, s1 = 0.f;
        #pragma unroll
        for (int r = 0; r < 16; ++r) {
            int e = (r & 3) + 8 * (r >> 2) + 4 * hi;
            bool in = ((uint)(e - lo) < (uint)(nx - lo));
            s0 += in ? y.a[r] : 0.f;
            s1 += in ? y.b[r] : 0.f;
        }
        s0 += __shfl_xor(s0, 32);
        s1 += __shfl_xor(s1, 32);
        int dseg = __builtin_amdgcn_readlane(dst, lo);
        atomicAdd(&agg[(size_t)dseg * H + lane], hi ? s1 : s0);
        lo = nx;
    }
}

// ---------------- edge/message kernel: block = 256 dst-sorted edges ----------------
__global__ __launch_bounds__(256, 5) void edge_mfma(
    const ushort* __restrict__ xbf, const uint4* __restrict__ eaLo,
    const uint* __restrict__ eaHi, const ushort2* __restrict__ nbrS,
    const ushort* __restrict__ wb,
    const float* __restrict__ b1, const float* __restrict__ b2,
    float* __restrict__ agg) {
    __shared__ __align__(16) ushort lds[10752];   // W1T [64][168] only
    {
        const uint4* s4 = (const uint4*)wb;
        uint4* d4 = (uint4*)lds;
        for (int i = threadIdx.x; i < 1344; i += 256) d4[i] = s4[i];
    }
    __syncthreads();
    const ushort* W1T = lds;

    const int lane = threadIdx.x & 63;
    const int wv   = threadIdx.x >> 6;
    const int hi   = lane >> 5;
    const int l31  = lane & 31;

    // XCD-bijective block swizzle: each XCD gets a contiguous dst-sorted span
    const int nwg = gridDim.x;
    const int q = nwg >> 3, rr = nwg & 7;
    const int xcd = blockIdx.x & 7, idx = blockIdx.x >> 3;
    const int swz = (xcd < rr) ? (xcd * (q + 1) + idx)
                               : (rr * (q + 1) + (xcd - rr) * q + idx);

    const int i0 = swz * 256 + wv * 64 + l31;
    const int i1 = i0 + 32;

    const ushort2 nd0 = nbrS[i0], nd1 = nbrS[i1];
    const int src0 = nd0.x, dst0 = nd0.y;
    const int src1 = nd1.x, dst1 = nd1.y;
    const uint4 elo0 = eaLo[i0], elo1 = eaLo[i1];
    const uint  ehi0 = eaHi[i0], ehi1 = eaHi[i1];

    // pinned frags (L2-hot): W2T, V1T, V2T
    short8 aW2[4][2], aV1[2], aV2[2];
    #pragma unroll
    for (int m = 0; m < 2; ++m) {
        int r = l31 + 32 * m;
        aV1[m] = *(const short8*)(wb + 15360 + r * 16 + hi * 8);
        aV2[m] = *(const short8*)(wb + 16384 + r * 16 + hi * 8);
        #pragma unroll
        for (int s = 0; s < 4; ++s)
            aW2[s][m] = *(const short8*)(wb + 10752 + r * 72 + s * 16 + hi * 8);
    }

    const float bias2_0 = b2[l31];
    const float bias2_1 = b2[l31 + 32];

    // ---- group 0 ----
    short8 bx0[8];
    gather_x(bx0, xbf, dst0, src0, hi);
    YPair y0 = msg_compute(bx0, elo0, ehi0, W1T, aW2, aV1, aV2,
                           b1, bias2_0, bias2_1, l31, hi);

    // prefetch group 1's x rows before group 0's reduce
    short8 bx1[8];
    gather_x(bx1, xbf, dst1, src1, hi);

    reduce_write(y0, dst0, agg, lane, l31, hi);

    // ---- group 1 ----
    YPair y1 = msg_compute(bx1, elo1, ehi1, W1T, aW2, aV1, aV2,
                           b1, bias2_0, bias2_1, l31, hi);
    reduce_write(y1, dst1, agg, lane, l31, hi);
}

// ---------------- node/update kernel: block = 128 nodes ----------------
__global__ __launch_bounds__(256, 4) void node_mfma(
    const ushort* __restrict__ xbf, const float* __restrict__ agg,
    const float* __restrict__ node_attr, const ushort* __restrict__ wb,
    const float* __restrict__ b1, const float* __restrict__ b2,
    ushort* __restrict__ xnext, float* __restrict__ outf, int last) {
    __shared__ __align__(16) ushort lds[8704];   // WU1T [64][136]
    {
        const uint4* s4 = (const uint4*)wb;
        uint4* d4 = (uint4*)lds;
        for (int i = threadIdx.x; i < 1088; i += 256) d4[i] = s4[i];
    }
    __syncthreads();
    const ushort* W1T = lds;

    const int lane = threadIdx.x & 63;
    const int wv   = threadIdx.x >> 6;
    const int hi   = lane >> 5;
    const int l31  = lane & 31;
    const int n    = blockIdx.x * 128 + wv * 32 + l31;
    const int nc   = n < NN ? n : NN - 1;

    short8 aW2[4][2], aV1[2], aV2[2];
    #pragma unroll
    for (int m = 0; m < 2; ++m) {
        int r = l31 + 32 * m;
        aV1[m] = *(const short8*)(wb + 13312 + r * 16 + hi * 8);
        aV2[m] = *(const short8*)(wb + 14336 + r * 16 + hi * 8);
        #pragma unroll
        for (int s = 0; s < 4; ++s)
            aW2[s][m] = *(const short8*)(wb + 8704 + r * 72 + s * 16 + hi * 8);
    }

    float na[AD];
    #pragma unroll
    for (int a = 0; a < AD; ++a) na[a] = node_attr[(size_t)nc * AD + a];

    U8 bna;
    {
        uint g0 = pkbf(na[0], na[1]), g1 = pkbf(na[2], na[3]);
        uint g2 = pkbf(na[4], na[5]), g3 = pkbf(na[6], na[7]);
        uint g8 = pkbf(na[8], 0.f);
        bna.u[0] = hi ? g8 : g0;
        bna.u[1] = hi ? 0u : g1;
        bna.u[2] = hi ? 0u : g2;
        bna.u[3] = hi ? 0u : g3;
    }
    f32x16 gA0 = {}, gA1 = {};
    gA0 = MFMA(aV1[0], bna.v, gA0);
    gA1 = MFMA(aV1[1], bna.v, gA1);

    f32x16 mA0 = {}, mA1 = {};
    #pragma unroll
    for (int s = 0; s < 8; ++s) {
        short8 bx;
        if (s < 4) {
            bx = *(const short8*)(xbf + (size_t)nc * H + s * 16 + hi * 8);
        } else {
            const float* ap = agg + (size_t)nc * H + (s - 4) * 16 + hi * 8;
            float4 u0 = *(const float4*)ap;
            float4 u1 = *(const float4*)(ap + 4);
            U8 q;
            q.u[0] = pkbf(u0.x, u0.y); q.u[1] = pkbf(u0.z, u0.w);
            q.u[2] = pkbf(u1.x, u1.y); q.u[3] = pkbf(u1.z, u1.w);
            bx = q.v;
        }
        short8 a0 = *(const short8*)(W1T + l31 * 136 + s * 16 + hi * 8);
        short8 a1 = *(const short8*)(W1T + (l31 + 32) * 136 + s * 16 + hi * 8);
        mA0 = MFMA(a0, bx, mA0);
        mA1 = MFMA(a1, bx, mA1);
    }

    short8 bm[4];
    #pragma unroll
    for (int m = 0; m < 2; ++m) {
        const f32x16 mc = m ? mA1 : mA0;
        const f32x16 gc = m ? gA1 : gA0;
        float y[16];
        #pragma unroll
        for (int r = 0; r < 16; ++r) {
            int h0 = (r & 3) + 8 * (r >> 2) + 32 * m;
            float bb = hi ? b1[h0 + 4] : b1[h0];
            y[r] = swish_fast(fmaf(mc[r], gc[r], bb));
        }
        pack16(y, &bm[2 * m]);
    }

    f32x16 h0a = {}, h1a = {};
    h0a = MFMA(aV2[0], bna.v, h0a);
    h1a = MFMA(aV2[1], bna.v, h1a);
    f32x16 p0 = {}, p1 = {};
    #pragma unroll
    for (int s = 0; s < 4; ++s) {
        p0 = MFMA(aW2[s][0], bm[s], p0);
        p1 = MFMA(aW2[s][1], bm[s], p1);
    }

    #pragma unroll
    for (int m = 0; m < 2; ++m) {
        const f32x16 mc = m ? p1 : p0;
        const f32x16 gc = m ? h1a : h0a;
        float y[16];
        #pragma unroll
        for (int r = 0; r < 16; ++r) {
            int h0 = (r & 3) + 8 * (r >> 2) + 32 * m;
            float bb = hi ? b2[h0 + 4] : b2[h0];
            y[r] = fmaf(mc[r], gc[r], bb);
        }
        #pragma unroll
        for (int g = 0; g < 2; ++g) {
            uint c0 = pkbf(y[g*8+0], y[g*8+1]);
            uint c1 = pkbf(y[g*8+2], y[g*8+3]);
            uint c2 = pkbf(y[g*8+4], y[g*8+5]);
            uint c3 = pkbf(y[g*8+6], y[g*8+7]);
            xhalf(c0, c2);
            xhalf(c1, c3);
            int goff = (2*m + g) * 16 + hi * 8;
            U8 xb; xb.v = *(const short8*)(xbf + (size_t)nc * H + goff);
            float o[8];
            uint cc[4] = {c0, c1, c2, c3};
            #pragma unroll
            for (int j = 0; j < 4; ++j) {
                o[2*j]   = 0.7f * bflo((uint)xb.u[j]) + 0.3f * bflo(cc[j]);
                o[2*j+1] = 0.7f * bfhi((uint)xb.u[j]) + 0.3f * bfhi(cc[j]);
            }
            if (n < NN) {
                if (last) {
                    float4 w0 = {o[0], o[1], o[2], o[3]};
                    float4 w1 = {o[4], o[5], o[6], o[7]};
                    *(float4*)(outf + (size_t)n * H + goff)     = w0;
                    *(float4*)(outf + (size_t)n * H + goff + 4) = w1;
                } else {
                    U8 q;
                    #pragma unroll
                    for (int j = 0; j < 4; ++j) q.u[j] = pkbf(o[2*j], o[2*j+1]);
                    *(short8*)(xnext + (size_t)n * H + goff) = q.v;
                }
            }
        }
    }
}

extern "C" void kernel_launch(void* const* d_in, const int* in_sizes, int n_in,
                              void* d_out, int out_size, void* d_ws, size_t ws_size,
                              hipStream_t stream) {
    const float* x         = (const float*)d_in[0];
    const float* edge_attr = (const float*)d_in[1];
    const float* node_attr = (const float*)d_in[2];
    const float* amf       = (const float*)d_in[3];
    const float* Wm1 = (const float*)d_in[4];
    const float* Vm1 = (const float*)d_in[5];
    const float* bm1 = (const float*)d_in[6];
    const float* Wm2 = (const float*)d_in[7];
    const float* Vm2 = (const float*)d_in[8];
    const float* bm2 = (const float*)d_in[9];
    const float* Wu1 = (const float*)d_in[10];
    const float* Vu1 = (const float*)d_in[11];
    const float* bu1 = (const float*)d_in[12];
    const float* Wu2 = (const float*)d_in[13];
    const float* Vu2 = (const float*)d_in[14];
    const float* bu2 = (const float*)d_in[15];
    const int*   ei  = (const int*)d_in[16];

    float* out = (float*)d_out;
    float* agg = (float*)d_out;     // agg shares d_out (per-block row ownership in node_mfma)

    // ---- workspace layout (16B-aligned blocks) ----
    ushort* xbf0  = (ushort*)d_ws;                   // NN*H
    ushort* xbf1  = xbf0 + (size_t)NN * H;           // NN*H
    ushort* wbE   = xbf1 + (size_t)NN * H;           // 2*17408
    ushort* wbN   = wbE + 2 * 17408;                 // 2*15360
    uint4*  eaLo  = (uint4*)(wbN + 2 * 15360);       // NE * 16B
    uint*   eaHi  = (uint*)(eaLo + NE);              // NE * 4B
    ushort2* nbrS = (ushort2*)(eaHi + NE);           // NE * 4B
    int* cnt      = (int*)(nbrS + NE);               // 51200
    int* btot     = cnt + 51200;                     // 256
    int* boff     = btot + 256;                      // 256
    int* partial  = boff + 256;                      // 51200
    int* cursor   = partial + 51200;                 // 50000

    prep_all<<<1563 + 256, 256, 0, stream>>>(x, xbf0, Wm1, Vm1, Wm2, Vm2,
                                             Wu1, Vu1, Wu2, Vu2, wbE, wbN);

    // ---- CSR build (once per call) ----
    hipMemsetAsync(cnt, 0, 51200 * sizeof(int), stream);
    hist_k<<<(NE + 255) / 256, 256, 0, stream>>>(ei, cnt);
    scan1_k<<<200, 256, 0, stream>>>(cnt, partial, btot);
    scan2_k<<<1, 256, 0, stream>>>(btot, boff);
    scan3_k<<<200, 256, 0, stream>>>(partial, boff, cursor);
    fill_k<<<(NE + 255) / 256, 256, 0, stream>>>(ei, edge_attr, amf, cursor,
                                                 nbrS, eaLo, eaHi);

    for (int l = 0; l < 2; ++l) {
        const ushort* xb = (l == 0) ? xbf0 : xbf1;
        hipMemsetAsync(agg, 0, (size_t)NN * H * sizeof(float), stream);
        edge_mfma<<<NE / 256, 256, 0, stream>>>(
            xb, eaLo, eaHi, nbrS, wbE + (size_t)l * 17408,
            bm1 + l * H, bm2 + l * H, agg);
        node_mfma<<<(NN + 127) / 128, 256, 0, stream>>>(
            xb, agg, node_attr, wbN + (size_t)l * 15360,
            bu1 + l * H, bu2 + l * H, xbf1, out, (l == 1) ? 1 : 0);
    }
}

// Round 6
// 297.899 us; speedup vs baseline: 1.2404x; 1.2404x over previous
//
#include <hip/hip_runtime.h>
#include <hip/hip_bf16.h>

#define NN 50000
#define NE 800000
#define H  64
#define AD 9

typedef __attribute__((ext_vector_type(8)))  short short8;
typedef __attribute__((ext_vector_type(16))) float f32x16;
typedef unsigned int uint;
typedef unsigned short ushort;

union U8 { short8 v; uint u[4]; ushort s[8]; };

__device__ __forceinline__ f32x16 MFMA(short8 a, short8 b, f32x16 c) {
    return __builtin_amdgcn_mfma_f32_32x32x16_bf16(a, b, c, 0, 0, 0);
}

__device__ __forceinline__ ushort f2bf(float v) {
    __hip_bfloat16 b = __float2bfloat16(v);
    return *(ushort*)&b;
}
__device__ __forceinline__ uint pkbf(float a, float b) {
    uint r;
    asm volatile("v_cvt_pk_bf16_f32 %0, %1, %2" : "=v"(r) : "v"(a), "v"(b));
    return r;
}
__device__ __forceinline__ float bflo(uint u) { return __uint_as_float(u << 16); }
__device__ __forceinline__ float bfhi(uint u) { return __uint_as_float(u & 0xffff0000u); }

__device__ __forceinline__ float swish_fast(float v) {
    return v * __builtin_amdgcn_rcpf(1.f + __expf(-v));
}

// {a,b} -> a' = {a.lo_lanes, b.lo_lanes}, b' = {a.hi_lanes, b.hi_lanes}
__device__ __forceinline__ void xhalf(uint& a, uint& b) {
    asm("v_permlane32_swap_b32 %0, %1" : "+v"(a), "+v"(b));
}

// pack 16 accum values (one 32-row C-half) into 2 bf16 frags (k=row order)
__device__ __forceinline__ void pack16(const float* y, short8* out) {
    #pragma unroll
    for (int g = 0; g < 2; ++g) {
        uint c0 = pkbf(y[g*8+0], y[g*8+1]);
        uint c1 = pkbf(y[g*8+2], y[g*8+3]);
        uint c2 = pkbf(y[g*8+4], y[g*8+5]);
        uint c3 = pkbf(y[g*8+6], y[g*8+7]);
        xhalf(c0, c2);
        xhalf(c1, c3);
        U8 q; q.u[0] = c0; q.u[1] = c1; q.u[2] = c2; q.u[3] = c3;
        out[g] = q.v;
    }
}

// ---------------- prep: x -> bf16 AND weights -> transposed/padded bf16 ----------------
__global__ void prep_all(const float* __restrict__ x, ushort* __restrict__ xb,
                         const float* __restrict__ Wm1, const float* __restrict__ Vm1,
                         const float* __restrict__ Wm2, const float* __restrict__ Vm2,
                         const float* __restrict__ Wu1, const float* __restrict__ Vu1,
                         const float* __restrict__ Wu2, const float* __restrict__ Vu2,
                         ushort* __restrict__ wbE, ushort* __restrict__ wbN) {
    const int b = blockIdx.x;
    if (b < 1563) {
        int t = b * 256 + threadIdx.x;
        if (t >= NN * H / 8) return;
        const float* p = x + (size_t)t * 8;
        U8 o;
        #pragma unroll
        for (int j = 0; j < 8; ++j) o.s[j] = f2bf(p[j]);
        *(short8*)(xb + (size_t)t * 8) = o.v;
        return;
    }
    int t = (b - 1563) * 256 + threadIdx.x;
    float v = 0.f;
    if (t < 2 * 17408) {
        int l = t / 17408, o = t % 17408;
        if (o < 10752)      { int h = o / 168, k = o % 168;            if (k < 129) v = Wm1[l*8256 + k*64 + h]; }
        else if (o < 15360) { int o2 = o-10752; int h = o2/72, k = o2%72; if (k < 64)  v = Wm2[l*4096 + k*64 + h]; }
        else if (o < 16384) { int o2 = o-15360; int h = o2/16, a = o2%16; if (a < 9)   v = Vm1[l*576 + a*64 + h]; }
        else                { int o2 = o-16384; int h = o2/16, a = o2%16; if (a < 9)   v = Vm2[l*576 + a*64 + h]; }
        wbE[t] = f2bf(v);
    } else if (t < 2 * 17408 + 2 * 15360) {
        int u = t - 2 * 17408;
        int l = u / 15360, o = u % 15360;
        if (o < 8704)       { int h = o / 136, k = o % 136;            if (k < 128) v = Wu1[l*8192 + k*64 + h]; }
        else if (o < 13312) { int o2 = o-8704;  int h = o2/72, k = o2%72; if (k < 64)  v = Wu2[l*4096 + k*64 + h]; }
        else if (o < 14336) { int o2 = o-13312; int h = o2/16, a = o2%16; if (a < 9)   v = Vu1[l*576 + a*64 + h]; }
        else                { int o2 = o-14336; int h = o2/16, a = o2%16; if (a < 9)   v = Vu2[l*576 + a*64 + h]; }
        wbN[u] = f2bf(v);
    }
}

// ---------------- CSR build ----------------
__global__ void hist_k(const int* __restrict__ ei, int* __restrict__ cnt) {
    int t = blockIdx.x * 256 + threadIdx.x;
    if (t < NE) atomicAdd(&cnt[ei[NE + t]], 1);
}

__global__ void scan1_k(const int* __restrict__ cnt, int* __restrict__ partial,
                        int* __restrict__ btot) {
    __shared__ int sh[256];
    const int b = blockIdx.x, tid = threadIdx.x, i = b * 256 + tid;
    int c = cnt[i];
    sh[tid] = c; __syncthreads();
    int run = c;
    for (int off = 1; off < 256; off <<= 1) {
        int t = (tid >= off) ? sh[tid - off] : 0;
        __syncthreads();
        run += t; sh[tid] = run; __syncthreads();
    }
    partial[i] = run - c;
    if (tid == 255) btot[b] = run;
}

__global__ void scan2_k(const int* __restrict__ btot, int* __restrict__ boff) {
    __shared__ int sh[256];
    const int tid = threadIdx.x;
    int c = (tid < 200) ? btot[tid] : 0;
    sh[tid] = c; __syncthreads();
    int run = c;
    for (int off = 1; off < 256; off <<= 1) {
        int t = (tid >= off) ? sh[tid - off] : 0;
        __syncthreads();
        run += t; sh[tid] = run; __syncthreads();
    }
    boff[tid] = run - c;
}

__global__ void scan3_k(const int* __restrict__ partial, const int* __restrict__ boff,
                        int* __restrict__ cursor) {
    int b = blockIdx.x, i = b * 256 + threadIdx.x;
    if (i < NN) cursor[i] = partial[i] + boff[b];
}

__global__ void fill_k(const int* __restrict__ ei, const float* __restrict__ edge_attr,
                       const float* __restrict__ amf, int* __restrict__ cursor,
                       ushort2* __restrict__ nbrS, uint4* __restrict__ eaLo,
                       uint* __restrict__ eaHi) {
    int e = blockIdx.x * 256 + threadIdx.x;
    if (e >= NE) return;
    const int dst = ei[NE + e], src = ei[e];
    const int pos = atomicAdd(&cursor[dst], 1);
    ushort2 nd; nd.x = (ushort)src; nd.y = (ushort)dst;
    nbrS[pos] = nd;
    float ea[AD];
    #pragma unroll
    for (int a = 0; a < AD; ++a) ea[a] = edge_attr[(size_t)e * AD + a];
    uint4 lo;
    lo.x = pkbf(ea[0], ea[1]); lo.y = pkbf(ea[2], ea[3]);
    lo.z = pkbf(ea[4], ea[5]); lo.w = pkbf(ea[6], ea[7]);
    eaLo[pos] = lo;
    eaHi[pos] = pkbf(ea[8], amf[e]);   // lo16 = ea[8], hi16 = amf
}

// ---------------- edge message compute (GEMM2 flipped: C2[e][h]) ----------------
struct YPair { f32x16 a, b; };

__device__ __forceinline__ YPair msg_compute(
    const short8 bx[8], uint4 elo, uint ehi,
    const ushort* __restrict__ W1T,
    const short8 aW2[4][2], const short8 aV1[2], const short8 aV2[2],
    const float* __restrict__ b1, float bias2_0, float bias2_1,
    int l31, int hi) {
    U8 bea;
    bea.u[0] = hi ? (ehi & 0xffffu) : elo.x;
    bea.u[1] = hi ? 0u : elo.y;
    bea.u[2] = hi ? 0u : elo.z;
    bea.u[3] = hi ? 0u : elo.w;

    // gate1 (orientation C[h][e])
    f32x16 gA0 = {}, gA1 = {};
    gA0 = MFMA(aV1[0], bea.v, gA0);
    gA1 = MFMA(aV1[1], bea.v, gA1);

    // GEMM1: m1T[h][e] = sum_k W1[k][h] * [x_i | x_j | amf][e][k]
    f32x16 mA0 = {}, mA1 = {};
    #pragma unroll
    for (int s = 0; s < 8; ++s) {
        short8 a0 = *(const short8*)(W1T + l31 * 168 + s * 16 + hi * 8);
        short8 a1 = *(const short8*)(W1T + (l31 + 32) * 168 + s * 16 + hi * 8);
        mA0 = MFMA(a0, bx[s], mA0);
        mA1 = MFMA(a1, bx[s], mA1);
    }
    {
        U8 ba;
        ba.u[0] = hi ? 0u : (ehi >> 16);
        ba.u[1] = 0; ba.u[2] = 0; ba.u[3] = 0;
        short8 a0 = *(const short8*)(W1T + l31 * 168 + 128 + hi * 8);
        short8 a1 = *(const short8*)(W1T + (l31 + 32) * 168 + 128 + hi * 8);
        mA0 = MFMA(a0, ba.v, mA0);
        mA1 = MFMA(a1, ba.v, mA1);
    }

    // swish(m1*gate1 + b1) -> frags (k=h_in, index=e) usable as GEMM2 A-operand
    short8 bm[4];
    #pragma unroll
    for (int m = 0; m < 2; ++m) {
        const f32x16 mc = m ? mA1 : mA0;
        const f32x16 gc = m ? gA1 : gA0;
        float y[16];
        #pragma unroll
        for (int r = 0; r < 16; ++r) {
            int h0 = (r & 3) + 8 * (r >> 2) + 32 * m;
            float bb = hi ? b1[h0 + 4] : b1[h0];
            y[r] = swish_fast(fmaf(mc[r], gc[r], bb));
        }
        pack16(y, &bm[2 * m]);
    }

    // flipped gate2 + GEMM2: C[m=e][n=h_out]
    f32x16 g2a = {}, g2b = {};
    g2a = MFMA(bea.v, aV2[0], g2a);
    g2b = MFMA(bea.v, aV2[1], g2b);
    f32x16 p0 = {}, p1 = {};
    #pragma unroll
    for (int s = 0; s < 4; ++s) {
        p0 = MFMA(bm[s], aW2[s][0], p0);
        p1 = MFMA(bm[s], aW2[s][1], p1);
    }

    YPair out;
    #pragma unroll
    for (int r = 0; r < 16; ++r) {
        out.a[r] = swish_fast(fmaf(p0[r], g2a[r], bias2_0));
        out.b[r] = swish_fast(fmaf(p1[r], g2b[r], bias2_1));
    }
    return out;
}

__device__ __forceinline__ void gather_x(short8 bx[8], const ushort* __restrict__ xbf,
                                         int dst, int src, int hi) {
    const ushort* xd = xbf + (size_t)dst * H;
    const ushort* xs = xbf + (size_t)src * H;
    #pragma unroll
    for (int s = 0; s < 8; ++s)
        bx[s] = *(const short8*)((s < 4 ? xd : xs) + (s & 3) * 16 + hi * 8);
}

// in-register segmented reduce over 32 dst-sorted edges (C rows), coalesced atomics
__device__ __forceinline__ void reduce_write(const YPair& y, int dst,
                                             float* __restrict__ agg,
                                             int lane, int l31, int hi) {
    int dp = __shfl_up(dst, 1);
    bool nb = (l31 != 0) && (dst != dp);
    uint mm = (uint)__ballot(nb);   // low 32 bits; halves mirror
    int lo = 0;
    while (lo < 32) {
        int nx = mm ? (int)__builtin_ctz(mm) : 32;
        mm &= mm - 1;
        float s0 = 0.f, s1 = 0.f;
        #pragma unroll
        for (int r = 0; r < 16; ++r) {
            int e = (r & 3) + 8 * (r >> 2) + 4 * hi;
            bool in = ((uint)(e - lo) < (uint)(nx - lo));
            s0 += in ? y.a[r] : 0.f;
            s1 += in ? y.b[r] : 0.f;
        }
        s0 += __shfl_xor(s0, 32);
        s1 += __shfl_xor(s1, 32);
        int dseg = __builtin_amdgcn_readlane(dst, lo);
        atomicAdd(&agg[(size_t)dseg * H + lane], hi ? s1 : s0);
        lo = nx;
    }
}

// ---------------- edge/message kernel: block = 256 dst-sorted edges ----------------
__global__ __launch_bounds__(256, 4) void edge_mfma(
    const ushort* __restrict__ xbf, const uint4* __restrict__ eaLo,
    const uint* __restrict__ eaHi, const ushort2* __restrict__ nbrS,
    const ushort* __restrict__ wb,
    const float* __restrict__ b1, const float* __restrict__ b2,
    float* __restrict__ agg) {
    __shared__ __align__(16) ushort lds[10752];   // W1T [64][168] only
    {
        const uint4* s4 = (const uint4*)wb;
        uint4* d4 = (uint4*)lds;
        for (int i = threadIdx.x; i < 1344; i += 256) d4[i] = s4[i];
    }
    __syncthreads();
    const ushort* W1T = lds;

    const int lane = threadIdx.x & 63;
    const int wv   = threadIdx.x >> 6;
    const int hi   = lane >> 5;
    const int l31  = lane & 31;

    const int i0 = blockIdx.x * 256 + wv * 64 + l31;
    const int i1 = i0 + 32;

    const ushort2 nd0 = nbrS[i0], nd1 = nbrS[i1];
    const int src0 = nd0.x, dst0 = nd0.y;
    const int src1 = nd1.x, dst1 = nd1.y;
    const uint4 elo0 = eaLo[i0], elo1 = eaLo[i1];
    const uint  ehi0 = eaHi[i0], ehi1 = eaHi[i1];

    // pinned frags (L2-hot): W2T, V1T, V2T
    short8 aW2[4][2], aV1[2], aV2[2];
    #pragma unroll
    for (int m = 0; m < 2; ++m) {
        int r = l31 + 32 * m;
        aV1[m] = *(const short8*)(wb + 15360 + r * 16 + hi * 8);
        aV2[m] = *(const short8*)(wb + 16384 + r * 16 + hi * 8);
        #pragma unroll
        for (int s = 0; s < 4; ++s)
            aW2[s][m] = *(const short8*)(wb + 10752 + r * 72 + s * 16 + hi * 8);
    }

    const float bias2_0 = b2[l31];
    const float bias2_1 = b2[l31 + 32];

    // ---- group 0 ----
    short8 bx0[8];
    gather_x(bx0, xbf, dst0, src0, hi);
    YPair y0 = msg_compute(bx0, elo0, ehi0, W1T, aW2, aV1, aV2,
                           b1, bias2_0, bias2_1, l31, hi);
    reduce_write(y0, dst0, agg, lane, l31, hi);

    // ---- group 1 ---- (no barriers in between: compiler may hoist these gathers)
    short8 bx1[8];
    gather_x(bx1, xbf, dst1, src1, hi);
    YPair y1 = msg_compute(bx1, elo1, ehi1, W1T, aW2, aV1, aV2,
                           b1, bias2_0, bias2_1, l31, hi);
    reduce_write(y1, dst1, agg, lane, l31, hi);
}

// ---------------- node/update kernel: block = 128 nodes ----------------
__global__ __launch_bounds__(256, 4) void node_mfma(
    const ushort* __restrict__ xbf, const float* __restrict__ agg,
    const float* __restrict__ node_attr, const ushort* __restrict__ wb,
    const float* __restrict__ b1, const float* __restrict__ b2,
    ushort* __restrict__ xnext, float* __restrict__ outf, int last) {
    __shared__ __align__(16) ushort lds[8704];   // WU1T [64][136]
    {
        const uint4* s4 = (const uint4*)wb;
        uint4* d4 = (uint4*)lds;
        for (int i = threadIdx.x; i < 1088; i += 256) d4[i] = s4[i];
    }
    __syncthreads();
    const ushort* W1T = lds;

    const int lane = threadIdx.x & 63;
    const int wv   = threadIdx.x >> 6;
    const int hi   = lane >> 5;
    const int l31  = lane & 31;
    const int n    = blockIdx.x * 128 + wv * 32 + l31;
    const int nc   = n < NN ? n : NN - 1;

    short8 aW2[4][2], aV1[2], aV2[2];
    #pragma unroll
    for (int m = 0; m < 2; ++m) {
        int r = l31 + 32 * m;
        aV1[m] = *(const short8*)(wb + 13312 + r * 16 + hi * 8);
        aV2[m] = *(const short8*)(wb + 14336 + r * 16 + hi * 8);
        #pragma unroll
        for (int s = 0; s < 4; ++s)
            aW2[s][m] = *(const short8*)(wb + 8704 + r * 72 + s * 16 + hi * 8);
    }

    float na[AD];
    #pragma unroll
    for (int a = 0; a < AD; ++a) na[a] = node_attr[(size_t)nc * AD + a];

    U8 bna;
    {
        uint g0 = pkbf(na[0], na[1]), g1 = pkbf(na[2], na[3]);
        uint g2 = pkbf(na[4], na[5]), g3 = pkbf(na[6], na[7]);
        uint g8 = pkbf(na[8], 0.f);
        bna.u[0] = hi ? g8 : g0;
        bna.u[1] = hi ? 0u : g1;
        bna.u[2] = hi ? 0u : g2;
        bna.u[3] = hi ? 0u : g3;
    }
    f32x16 gA0 = {}, gA1 = {};
    gA0 = MFMA(aV1[0], bna.v, gA0);
    gA1 = MFMA(aV1[1], bna.v, gA1);

    f32x16 mA0 = {}, mA1 = {};
    #pragma unroll
    for (int s = 0; s < 8; ++s) {
        short8 bx;
        if (s < 4) {
            bx = *(const short8*)(xbf + (size_t)nc * H + s * 16 + hi * 8);
        } else {
            const float* ap = agg + (size_t)nc * H + (s - 4) * 16 + hi * 8;
            float4 u0 = *(const float4*)ap;
            float4 u1 = *(const float4*)(ap + 4);
            U8 q;
            q.u[0] = pkbf(u0.x, u0.y); q.u[1] = pkbf(u0.z, u0.w);
            q.u[2] = pkbf(u1.x, u1.y); q.u[3] = pkbf(u1.z, u1.w);
            bx = q.v;
        }
        short8 a0 = *(const short8*)(W1T + l31 * 136 + s * 16 + hi * 8);
        short8 a1 = *(const short8*)(W1T + (l31 + 32) * 136 + s * 16 + hi * 8);
        mA0 = MFMA(a0, bx, mA0);
        mA1 = MFMA(a1, bx, mA1);
    }

    short8 bm[4];
    #pragma unroll
    for (int m = 0; m < 2; ++m) {
        const f32x16 mc = m ? mA1 : mA0;
        const f32x16 gc = m ? gA1 : gA0;
        float y[16];
        #pragma unroll
        for (int r = 0; r < 16; ++r) {
            int h0 = (r & 3) + 8 * (r >> 2) + 32 * m;
            float bb = hi ? b1[h0 + 4] : b1[h0];
            y[r] = swish_fast(fmaf(mc[r], gc[r], bb));
        }
        pack16(y, &bm[2 * m]);
    }

    f32x16 h0a = {}, h1a = {};
    h0a = MFMA(aV2[0], bna.v, h0a);
    h1a = MFMA(aV2[1], bna.v, h1a);
    f32x16 p0 = {}, p1 = {};
    #pragma unroll
    for (int s = 0; s < 4; ++s) {
        p0 = MFMA(aW2[s][0], bm[s], p0);
        p1 = MFMA(aW2[s][1], bm[s], p1);
    }

    #pragma unroll
    for (int m = 0; m < 2; ++m) {
        const f32x16 mc = m ? p1 : p0;
        const f32x16 gc = m ? h1a : h0a;
        float y[16];
        #pragma unroll
        for (int r = 0; r < 16; ++r) {
            int h0 = (r & 3) + 8 * (r >> 2) + 32 * m;
            float bb = hi ? b2[h0 + 4] : b2[h0];
            y[r] = fmaf(mc[r], gc[r], bb);
        }
        #pragma unroll
        for (int g = 0; g < 2; ++g) {
            uint c0 = pkbf(y[g*8+0], y[g*8+1]);
            uint c1 = pkbf(y[g*8+2], y[g*8+3]);
            uint c2 = pkbf(y[g*8+4], y[g*8+5]);
            uint c3 = pkbf(y[g*8+6], y[g*8+7]);
            xhalf(c0, c2);
            xhalf(c1, c3);
            int goff = (2*m + g) * 16 + hi * 8;
            U8 xb; xb.v = *(const short8*)(xbf + (size_t)nc * H + goff);
            float o[8];
            uint cc[4] = {c0, c1, c2, c3};
            #pragma unroll
            for (int j = 0; j < 4; ++j) {
                o[2*j]   = 0.7f * bflo((uint)xb.u[j]) + 0.3f * bflo(cc[j]);
                o[2*j+1] = 0.7f * bfhi((uint)xb.u[j]) + 0.3f * bfhi(cc[j]);
            }
            if (n < NN) {
                if (last) {
                    float4 w0 = {o[0], o[1], o[2], o[3]};
                    float4 w1 = {o[4], o[5], o[6], o[7]};
                    *(float4*)(outf + (size_t)n * H + goff)     = w0;
                    *(float4*)(outf + (size_t)n * H + goff + 4) = w1;
                } else {
                    U8 q;
                    #pragma unroll
                    for (int j = 0; j < 4; ++j) q.u[j] = pkbf(o[2*j], o[2*j+1]);
                    *(short8*)(xnext + (size_t)n * H + goff) = q.v;
                }
            }
        }
    }
}

extern "C" void kernel_launch(void* const* d_in, const int* in_sizes, int n_in,
                              void* d_out, int out_size, void* d_ws, size_t ws_size,
                              hipStream_t stream) {
    const float* x         = (const float*)d_in[0];
    const float* edge_attr = (const float*)d_in[1];
    const float* node_attr = (const float*)d_in[2];
    const float* amf       = (const float*)d_in[3];
    const float* Wm1 = (const float*)d_in[4];
    const float* Vm1 = (const float*)d_in[5];
    const float* bm1 = (const float*)d_in[6];
    const float* Wm2 = (const float*)d_in[7];
    const float* Vm2 = (const float*)d_in[8];
    const float* bm2 = (const float*)d_in[9];
    const float* Wu1 = (const float*)d_in[10];
    const float* Vu1 = (const float*)d_in[11];
    const float* bu1 = (const float*)d_in[12];
    const float* Wu2 = (const float*)d_in[13];
    const float* Vu2 = (const float*)d_in[14];
    const float* bu2 = (const float*)d_in[15];
    const int*   ei  = (const int*)d_in[16];

    float* out = (float*)d_out;
    float* agg = (float*)d_out;     // agg shares d_out (per-block row ownership in node_mfma)

    // ---- workspace layout (16B-aligned blocks) ----
    ushort* xbf0  = (ushort*)d_ws;                   // NN*H
    ushort* xbf1  = xbf0 + (size_t)NN * H;           // NN*H
    ushort* wbE   = xbf1 + (size_t)NN * H;           // 2*17408
    ushort* wbN   = wbE + 2 * 17408;                 // 2*15360
    uint4*  eaLo  = (uint4*)(wbN + 2 * 15360);       // NE * 16B
    uint*   eaHi  = (uint*)(eaLo + NE);              // NE * 4B
    ushort2* nbrS = (ushort2*)(eaHi + NE);           // NE * 4B
    int* cnt      = (int*)(nbrS + NE);               // 51200
    int* btot     = cnt + 51200;                     // 256
    int* boff     = btot + 256;                      // 256
    int* partial  = boff + 256;                      // 51200
    int* cursor   = partial + 51200;                 // 50000

    prep_all<<<1563 + 256, 256, 0, stream>>>(x, xbf0, Wm1, Vm1, Wm2, Vm2,
                                             Wu1, Vu1, Wu2, Vu2, wbE, wbN);

    // ---- CSR build (once per call) ----
    hipMemsetAsync(cnt, 0, 51200 * sizeof(int), stream);
    hist_k<<<(NE + 255) / 256, 256, 0, stream>>>(ei, cnt);
    scan1_k<<<200, 256, 0, stream>>>(cnt, partial, btot);
    scan2_k<<<1, 256, 0, stream>>>(btot, boff);
    scan3_k<<<200, 256, 0, stream>>>(partial, boff, cursor);
    fill_k<<<(NE + 255) / 256, 256, 0, stream>>>(ei, edge_attr, amf, cursor,
                                                 nbrS, eaLo, eaHi);

    for (int l = 0; l < 2; ++l) {
        const ushort* xb = (l == 0) ? xbf0 : xbf1;
        hipMemsetAsync(agg, 0, (size_t)NN * H * sizeof(float), stream);
        edge_mfma<<<NE / 256, 256, 0, stream>>>(
            xb, eaLo, eaHi, nbrS, wbE + (size_t)l * 17408,
            bm1 + l * H, bm2 + l * H, agg);
        node_mfma<<<(NN + 127) / 128, 256, 0, stream>>>(
            xb, agg, node_attr, wbN + (size_t)l * 15360,
            bu1 + l * H, bu2 + l * H, xbf1, out, (l == 1) ? 1 : 0);
    }
}